// Round 13
// baseline (126.123 us; speedup 1.0000x reference)
//
#include <hip/hip_runtime.h>

// Problem dims (fixed by reference setup_inputs)
#define B_  4
#define C_  3
#define S_  5
#define M_  18
#define HW  45056            // 256*176
#define HW4 (HW/4)           // 11264 float4s per plane/channel
#define SPLIT 4              // chunks per (plane,channel) (ITERS=11 proven)
#define TPB 256
#define CHUNK4 (HW4/SPLIT)   // 2816 float4s per chunk
#define ITERS (CHUNK4/TPB)   // 11 iterations per thread
#define NPLANE (B_*S_*M_)    // 360
#define NBLK (NPLANE*C_*SPLIT) // 4320 blocks (4320 % 8 == 0 -> bijective swizzle)
#define NV 6                 // per-block outputs: msum + {wx,wy,wxx,wyy,wxy}

// ============================= DESIGN LEDGER =============================
// Wall noise is +-3-6us (R12 == R6 code measured 122.5 vs 116.4). Only
// deltas >6us are real. Harness ops (~84us: 268MB poison fill @82% HBM
// peak + 65MB mask restore copy) are untouchable and AT roofline.
// Moments kernel history: 7-stream interleave (R6 champion) is latency-
// bound (R4/R7/R10: HBM<=12%, VALU<=23%, Occ 17-26%) at VGPR 88 ->
// 5 waves/SIMD. Failed fixes: nt (+8.5), mask reg-staging (+8), forced
// occupancy (spills +130), prefetch ring (+4), G-share reg/L1 (+8-10),
// flag-fusion (+10/+35). hipcc's schedule is the HIP-level local optimum
// for that structure.
// THIS round: channel-split. One channel per block -> 3 load streams,
// 6 accumulators, ~50 VGPR -> 8 waves/SIMD NATURALLY (no forcing, no
// spill: register need genuinely shrinks, unlike R8). 3x waves (17280),
// shorter chains. Cost: mask read 3x = 195MB from L3 (restore-copy
// resident; Infinity Cache BW >> HBM). Work conserved.
// =========================================================================

// Kernel A: per-(plane,channel,chunk) partial sums of 6 weighted RAW moments.
// Rescale deferred to epilogue (exact affine transform in double).
__global__ __launch_bounds__(TPB) void moments_kernel(
    const float4* __restrict__ X, const float4* __restrict__ Y,
    const float4* __restrict__ Mk, float* __restrict__ part) {
  // XCD-aware bijective swizzle (NBLK % 8 == 0).
  int wg     = (blockIdx.x & 7) * (NBLK / 8) + (blockIdx.x >> 3);
  int pc     = wg / SPLIT;           // plane*C_ + c
  int chunk  = wg - pc * SPLIT;
  int plane  = pc / C_;
  int c      = pc - plane * C_;
  int b      = plane / (S_ * M_);

  const float4* mp = Mk + (size_t)plane * HW4;
  const float4* xp = X  + (size_t)(b * C_ + c) * HW4;
  const float4* yp = Y  + (size_t)(b * C_ + c) * HW4;

  int base = chunk * CHUNK4 + (int)threadIdx.x;

  float aW = 0.f, s1 = 0.f, s2 = 0.f, s11 = 0.f, s22 = 0.f, s12 = 0.f;

#pragma unroll
  for (int it = 0; it < ITERS; ++it) {
    int i = base + it * TPB;
    float4 w  = mp[i];               // L3-resident (restore copy)
    float4 xv = xp[i];               // L2-resident
    float4 yv = yp[i];
    float wf[4] = {w.x,  w.y,  w.z,  w.w};
    float xf[4] = {xv.x, xv.y, xv.z, xv.w};
    float yf[4] = {yv.x, yv.y, yv.z, yv.w};
#pragma unroll
    for (int j = 0; j < 4; ++j) {
      float xc = xf[j], yc = yf[j], wc = wf[j];
      float wx = wc * xc;
      float wy = wc * yc;
      aW  += wc;
      s1  += wx;
      s2  += wy;
      s11  = fmaf(wx, xc, s11);
      s22  = fmaf(wy, yc, s22);
      s12  = fmaf(wx, yc, s12);
    }
  }

  // 6 values: [0]=msum, [1..5]={wx,wy,wxx,wyy,wxy} (raw)
  float v[NV] = {aW, s1, s2, s11, s22, s12};

  // wave-64 butterfly reduce (6 values — cheap)
#pragma unroll
  for (int off = 32; off > 0; off >>= 1) {
#pragma unroll
    for (int j = 0; j < NV; ++j) v[j] += __shfl_xor(v[j], off);
  }

  __shared__ float red[TPB/64][NV];
  int lane = threadIdx.x & 63;
  int wv   = threadIdx.x >> 6;
  if (lane == 0) {
#pragma unroll
    for (int j = 0; j < NV; ++j) red[wv][j] = v[j];
  }
  __syncthreads();
  if (threadIdx.x < NV) {
    float s = (red[0][threadIdx.x] + red[1][threadIdx.x]) +
              (red[2][threadIdx.x] + red[3][threadIdx.x]);
    part[(size_t)wg * NV + threadIdx.x] = s;
  }
}

// Kernel B: tiny epilogue, one block. Plain loads (kernel-boundary coherence).
// Exact affine rescale of raw moments in double:
//   xs = 0.5x + 0.5  =>  E[w*xs]    = 0.5*S1 + 0.5*W
//                        E[w*xs^2]  = 0.25*S11 + 0.5*S1 + 0.25*W
//                        E[w*xs*ys] = 0.25*(S12 + S1 + S2 + W)
__global__ __launch_bounds__(384) void finalize_kernel(
    const float* __restrict__ part, float* __restrict__ out) {
  __shared__ float csS[NPLANE], ssS[NPLANE];
  __shared__ double csb[B_*S_], ssb[B_*S_];
  int t = threadIdx.x;

  if (t < NPLANE) {
    // W from the c=0 sections (every c computed it; they're identical).
    double W = 0.0;
    for (int ch = 0; ch < SPLIT; ++ch)
      W += (double)part[(size_t)((t * C_ + 0) * SPLIT + ch) * NV + 0];

    const double C1d = 1e-4, C2d = 9e-4;
    double inv = 1.0 / (W + 1e-6);
    double csAcc = 0.0, ssAcc = 0.0;
#pragma unroll
    for (int c = 0; c < C_; ++c) {
      double S1 = 0.0, S2 = 0.0, S11 = 0.0, S22 = 0.0, S12 = 0.0;
      for (int ch = 0; ch < SPLIT; ++ch) {
        const float* p = part + (size_t)((t * C_ + c) * SPLIT + ch) * NV;
        S1  += (double)p[1];
        S2  += (double)p[2];
        S11 += (double)p[3];
        S22 += (double)p[4];
        S12 += (double)p[5];
      }
      double mu1  = (0.5*S1 + 0.5*W) * inv;
      double mu2  = (0.5*S2 + 0.5*W) * inv;
      double mu11 = (0.25*S11 + 0.5*S1 + 0.25*W) * inv;
      double mu22 = (0.25*S22 + 0.5*S2 + 0.25*W) * inv;
      double mu12 = (0.25*(S12 + S1 + S2 + W)) * inv;
      double m1s = mu1*mu1, m2s = mu2*mu2, m12 = mu1*mu2;
      double sig1  = mu11 - m1s;
      double sig2  = mu22 - m2s;
      double sig12 = mu12 - m12;
      double cs   = (2.0*sig12 + C2d) / (sig1 + sig2 + C2d);
      double ssim = (2.0*m12 + C1d) / (m1s + m2s + C1d) * cs;
      if (cs   < 0.0) cs   = 0.0;
      if (ssim < 0.0) ssim = 0.0;
      csAcc += cs; ssAcc += ssim;
    }
    csS[t] = (float)csAcc;
    ssS[t] = (float)ssAcc;
  }
  __syncthreads();

  if (t < B_*S_) {  // t = b*S_ + s
    double cb = 0.0, sb = 0.0;
    for (int m = 0; m < M_; ++m) { cb += (double)csS[t*M_ + m]; sb += (double)ssS[t*M_ + m]; }
    csb[t] = cb / (double)(M_*C_);
    ssb[t] = sb / (double)(M_*C_);
  }
  __syncthreads();

  if (t == 0) {
    double acc = 0.0;
    for (int b = 0; b < B_; ++b) {
      double p = ssb[b*S_ + (S_-1)];
      for (int s = 0; s < S_-1; ++s) p *= csb[b*S_ + s];
      acc += p;
    }
    out[0] = (float)(acc / (double)B_);
  }
}

extern "C" void kernel_launch(void* const* d_in, const int* in_sizes, int n_in,
                              void* d_out, int out_size, void* d_ws, size_t ws_size,
                              hipStream_t stream) {
  (void)in_sizes; (void)n_in; (void)out_size; (void)ws_size;
  const float4* X  = (const float4*)d_in[0];
  const float4* Y  = (const float4*)d_in[1];
  const float4* Mk = (const float4*)d_in[2];
  float* part = (float*)d_ws;        // 4320*6*4 = 103680 B
  float* out  = (float*)d_out;

  hipLaunchKernelGGL(moments_kernel, dim3(NBLK), dim3(TPB), 0, stream,
                     X, Y, Mk, part);
  hipLaunchKernelGGL(finalize_kernel, dim3(1), dim3(384), 0, stream, part, out);
}

// Round 14
// 121.731 us; speedup vs baseline: 1.0361x; 1.0361x over previous
//
#include <hip/hip_runtime.h>

// Problem dims (fixed by reference setup_inputs)
#define B_  4
#define C_  3
#define S_  5
#define M_  18
#define HW  45056            // 256*176
#define HW4 (HW/4)           // 11264 float4s per plane/channel
#define SPLIT 4              // blocks per (b,s,m) plane (divides HW4/TPB = 44)
#define TPB 256
#define CHUNK4 (HW4/SPLIT)   // 2816 float4s per block
#define ITERS (CHUNK4/TPB)   // 11 iterations per thread
#define NPLANE (B_*S_*M_)    // 360
#define NBLK (NPLANE*SPLIT)  // 1440 blocks (1440 % 8 == 0 -> bijective XCD swizzle)

// ============================= DESIGN LEDGER =============================
// CHAMPION (R6 == R12 file; measured 116.4 / 122.5 us — noise band ±3-6us).
// Harness floor ~84us: 268MB ws poison fill @82% HBM peak + 65MB mask
// restore copy. Both AT the HBM-write roofline — untouchable.
// Moments phase: memory-LATENCY wall, ~30-43us. Four structurally distinct
// kernels (R4/R7/R10/R13: 480-4320 blocks, 44-128 VGPR, 3-7 load streams)
// all land 42-47us with HBM<=12%, VALU<=27%, regardless of occupancy
// (17-35%) — per-CU outstanding-request capacity serving scattered
// L2/L3/HBM round trips is the binding resource; adding waves/registers/
// streams doesn't add MLP. Ten interventions, all null-to-negative:
//   nt mask loads           +8.5us (R9 clean A/B — forfeits L3 residency)
//   mask reg-staging        +8us   (R7 — VGPR 88, occupancy loss)
//   forced VGPR<=32         +130us (R8 — accumulator spills, 305MB scratch)
//   depth-2 prefetch ring   +4us   (R11 — displaces compiler schedule)
//   G-share via registers   +8-10us(R1/R2 — 3x fewer waves)
//   G-share via L1 lockstep +8us   (R10 — barrier cost, FETCH unchanged)
//   LDS-transpose reduce    null   (R3 — butterfly fine at ITERS=11)
//   flag-fusion, rel/acq    +35us  (R4 — per-block buffer_wbl2 L2 scans)
//   flag-fusion, relaxed    +70us  (R5 — scalar sc1 coherence-point loads)
//   channel-split 3x blocks null   (R13 — occupancy 2x, duration unchanged)
// hipcc's schedule of this interleaved 7-stream loop is the HIP-level
// optimum found. Wall accounting: 84 harness + ~30 moments + ~4 finalize
// + gaps ~= 118us. This file is the exact champion revert.
// =========================================================================

// Kernel A: per-(plane,chunk) partial sums of the 16 weighted RAW moments.
// Rescale is deferred to the epilogue (exact affine transform in double).
__global__ __launch_bounds__(TPB) void moments_kernel(
    const float4* __restrict__ X, const float4* __restrict__ Y,
    const float4* __restrict__ Mk, float* __restrict__ part) {
  // XCD-aware bijective swizzle: each XCD's L2 holds ~1 batch of X/Y.
  int wg    = (blockIdx.x & 7) * (NBLK / 8) + (blockIdx.x >> 3);
  int plane = wg / SPLIT;           // (b,s,m)
  int chunk = wg - plane * SPLIT;
  int b     = plane / (S_ * M_);

  const float4* mp = Mk + (size_t)plane * HW4;
  const float4* xp = X  + (size_t)b * (C_ * HW4);
  const float4* yp = Y  + (size_t)b * (C_ * HW4);

  int base = chunk * CHUNK4 + (int)threadIdx.x;

  float aW = 0.f;
  float a1[C_], a2[C_], a11[C_], a22[C_], a12[C_];
#pragma unroll
  for (int c = 0; c < C_; ++c) { a1[c]=a2[c]=a11[c]=a22[c]=a12[c]=0.f; }

#pragma unroll
  for (int it = 0; it < ITERS; ++it) {
    int i = base + it * TPB;
    // Plain cached loads; interleaved 7-stream loop; compiler-scheduled.
    float4 w  = mp[i];
    aW += (w.x + w.y) + (w.z + w.w);
    float wf[4] = {w.x, w.y, w.z, w.w};
#pragma unroll
    for (int c = 0; c < C_; ++c) {
      float4 xv = xp[c * HW4 + i];
      float4 yv = yp[c * HW4 + i];
      float xf[4] = {xv.x, xv.y, xv.z, xv.w};
      float yf[4] = {yv.x, yv.y, yv.z, yv.w};
#pragma unroll
      for (int j = 0; j < 4; ++j) {
        float xc = xf[j], yc = yf[j], wc = wf[j];
        float wx = wc * xc;
        float wy = wc * yc;
        a1 [c] += wx;
        a2 [c] += wy;
        a11[c]  = fmaf(wx, xc, a11[c]);
        a22[c]  = fmaf(wy, yc, a22[c]);
        a12[c]  = fmaf(wx, yc, a12[c]);
      }
    }
  }

  // Pack 16 values: [0]=msum, then per channel {wx, wy, wxx, wyy, wxy} (raw)
  float v[16];
  v[0] = aW;
#pragma unroll
  for (int c = 0; c < C_; ++c) {
    v[1 + c*5 + 0] = a1[c];
    v[1 + c*5 + 1] = a2[c];
    v[1 + c*5 + 2] = a11[c];
    v[1 + c*5 + 3] = a22[c];
    v[1 + c*5 + 4] = a12[c];
  }

  // wave-64 butterfly reduce (amortized over the 11-iter main loop)
#pragma unroll
  for (int off = 32; off > 0; off >>= 1) {
#pragma unroll
    for (int j = 0; j < 16; ++j) v[j] += __shfl_xor(v[j], off);
  }

  __shared__ float red[TPB/64][16];
  int lane = threadIdx.x & 63;
  int wv   = threadIdx.x >> 6;
  if (lane == 0) {
#pragma unroll
    for (int j = 0; j < 16; ++j) red[wv][j] = v[j];
  }
  __syncthreads();
  if (threadIdx.x < 16) {
    float s = (red[0][threadIdx.x] + red[1][threadIdx.x]) +
              (red[2][threadIdx.x] + red[3][threadIdx.x]);
    part[(size_t)wg * 16 + threadIdx.x] = s;
  }
}

// Kernel B: tiny epilogue, one block. Plain loads (kernel-boundary coherence).
// Exact affine rescale of raw moments in double:
//   xs = 0.5x + 0.5  =>  E[w*xs]    = 0.5*S1 + 0.5*W
//                        E[w*xs^2]  = 0.25*S11 + 0.5*S1 + 0.25*W
//                        E[w*xs*ys] = 0.25*(S12 + S1 + S2 + W)
__global__ __launch_bounds__(384) void finalize_kernel(
    const float* __restrict__ part, float* __restrict__ out) {
  __shared__ float csS[NPLANE], ssS[NPLANE];
  __shared__ double csb[B_*S_], ssb[B_*S_];
  int t = threadIdx.x;

  if (t < NPLANE) {
    double s[16];
#pragma unroll
    for (int j = 0; j < 16; ++j) s[j] = 0.0;
    for (int ch = 0; ch < SPLIT; ++ch) {
      const float* p = part + (size_t)(t * SPLIT + ch) * 16;
#pragma unroll
      for (int j = 0; j < 16; ++j) s[j] += (double)p[j];
    }
    const double C1d = 1e-4, C2d = 9e-4;
    double W = s[0];
    double inv = 1.0 / (W + 1e-6);
    double csAcc = 0.0, ssAcc = 0.0;
#pragma unroll
    for (int c = 0; c < C_; ++c) {
      double S1  = s[1 + c*5 + 0];
      double S2  = s[1 + c*5 + 1];
      double S11 = s[1 + c*5 + 2];
      double S22 = s[1 + c*5 + 3];
      double S12 = s[1 + c*5 + 4];
      double mu1  = (0.5*S1 + 0.5*W) * inv;
      double mu2  = (0.5*S2 + 0.5*W) * inv;
      double mu11 = (0.25*S11 + 0.5*S1 + 0.25*W) * inv;
      double mu22 = (0.25*S22 + 0.5*S2 + 0.25*W) * inv;
      double mu12 = (0.25*(S12 + S1 + S2 + W)) * inv;
      double m1s = mu1*mu1, m2s = mu2*mu2, m12 = mu1*mu2;
      double sig1  = mu11 - m1s;
      double sig2  = mu22 - m2s;
      double sig12 = mu12 - m12;
      double cs   = (2.0*sig12 + C2d) / (sig1 + sig2 + C2d);
      double ssim = (2.0*m12 + C1d) / (m1s + m2s + C1d) * cs;
      if (cs   < 0.0) cs   = 0.0;
      if (ssim < 0.0) ssim = 0.0;
      csAcc += cs; ssAcc += ssim;
    }
    csS[t] = (float)csAcc;
    ssS[t] = (float)ssAcc;
  }
  __syncthreads();

  if (t < B_*S_) {  // t = b*S_ + s
    double cb = 0.0, sb = 0.0;
    for (int m = 0; m < M_; ++m) { cb += (double)csS[t*M_ + m]; sb += (double)ssS[t*M_ + m]; }
    csb[t] = cb / (double)(M_*C_);
    ssb[t] = sb / (double)(M_*C_);
  }
  __syncthreads();

  if (t == 0) {
    double acc = 0.0;
    for (int b = 0; b < B_; ++b) {
      double p = ssb[b*S_ + (S_-1)];
      for (int s = 0; s < S_-1; ++s) p *= csb[b*S_ + s];
      acc += p;
    }
    out[0] = (float)(acc / (double)B_);
  }
}

extern "C" void kernel_launch(void* const* d_in, const int* in_sizes, int n_in,
                              void* d_out, int out_size, void* d_ws, size_t ws_size,
                              hipStream_t stream) {
  (void)in_sizes; (void)n_in; (void)out_size; (void)ws_size;
  const float4* X  = (const float4*)d_in[0];
  const float4* Y  = (const float4*)d_in[1];
  const float4* Mk = (const float4*)d_in[2];
  float* part = (float*)d_ws;        // 1440*16*4 = 92160 B
  float* out  = (float*)d_out;

  hipLaunchKernelGGL(moments_kernel, dim3(NBLK), dim3(TPB), 0, stream,
                     X, Y, Mk, part);
  hipLaunchKernelGGL(finalize_kernel, dim3(1), dim3(384), 0, stream, part, out);
}